// Round 3
// baseline (403.884 us; speedup 1.0000x reference)
//
#include <hip/hip_runtime.h>
#include <hip/hip_bf16.h>

// DEChannelPool: 6 soft-morphology branches + per-channel BN + 1x1 conv + BN + ReLU.
// Inputs: fp32. Output: fp32 (reference output dtype is float32).
// Trick 1: exp(beta*(w±x)) = exp(beta*w)*exp(±beta*x): 2 exps per input pixel (shifted
//          by M for fp32 range), reused across all taps/branches.
// Trick 2: BN+conv fold to alpha*log(S) + const; const cancels in the final scalar BN.

#define BETA 15.0f
#define MSHIFT 25.0f
#define INV_BETA (1.0f/15.0f)
#define EPSB 1e-5f
#define Hn 192
#define Wn 192
#define HWn (192*192)
#define N1 (8*192*192)
#define TILE 32
#define HALO 3
#define TDIM 38
#define TSTR 39
#define NTW 6
#define SFLOOR 1e-37f

// workspace layout (float offsets)
#define WS_SUM   0
#define WS_SQS   384
#define WS_SCAL  768
#define WS_ALPHA 772
#define WS_WG    1156
#define WS_YE    4612
#define WS_YD    (4612 + 294912)
#define WS_TOTAL (4612 + 2*294912)

__global__ void k_wexp(const float* __restrict__ we,
                       const float* __restrict__ wd,
                       float* __restrict__ wg) {
    int idx = blockIdx.x * 256 + threadIdx.x;
    if (idx >= 3456) return;
    int kb = idx / 576;            // 0..5 (0-2 erosion, 3-5 dilation)
    int rem = idx - kb * 576;      // c*9 + tap
    float w = (kb < 3) ? we[kb * 576 + rem] : wd[(kb - 3) * 576 + rem];
    wg[idx] = __expf(BETA * w);
}

__global__ __launch_bounds__(256) void k_morph_stats(
    const float* __restrict__ x, const float* __restrict__ wg,
    float* __restrict__ sum, float* __restrict__ sqs) {
    __shared__ float2 E[TDIM * TSTR];
    __shared__ float redS[4][6], redQ[4][6];
    const int tid = threadIdx.x;
    const int p = blockIdx.y;            // b*64 + c
    const int c = p & 63;
    const int t = blockIdx.x;
    const int h0 = (t / NTW) * TILE, w0 = (t % NTW) * TILE;
    const float* xp = x + (size_t)p * HWn;
    const float em0 = __expf(-MSHIFT);

    for (int l = tid; l < TDIM * TDIM; l += 256) {
        int r = l / TDIM, cc = l - r * TDIM;
        int gh = h0 - HALO + r, gw = w0 - HALO + cc;
        float2 e;
        if (gh >= 0 && gh < Hn && gw >= 0 && gw < Wn) {
            float bx = BETA * xp[gh * Wn + gw];
            e.x = __expf(-bx - MSHIFT);   // erosion term
            e.y = __expf(bx - MSHIFT);    // dilation term
        } else { e.x = em0; e.y = em0; }  // zero padding -> x=0
        E[r * TSTR + cc] = e;
    }
    __syncthreads();

    const int px = (tid & 31) + HALO;
    const int py0 = (tid >> 5) * 4;      // 4-row vertical strip per thread
    float s[6] = {0,0,0,0,0,0}, q[6] = {0,0,0,0,0,0};
#pragma unroll
    for (int br = 0; br < 3; ++br) {
        const int d = br + 1;
        float WE[9], WD[9];
#pragma unroll
        for (int k2 = 0; k2 < 9; ++k2) {
            WE[k2] = wg[(br * 64 + c) * 9 + k2];
            WD[k2] = wg[((br + 3) * 64 + c) * 9 + k2];
        }
        const int nr = 4 + 2 * d;
        float2 colv[10][3];
#pragma unroll
        for (int r = 0; r < nr; ++r)
#pragma unroll
            for (int j = 0; j < 3; ++j)
                colv[r][j] = E[(py0 - d + r + HALO) * TSTR + px + (j - 1) * d];
#pragma unroll
        for (int k = 0; k < 4; ++k) {
            float SE = 0.f, SD = 0.f;
#pragma unroll
            for (int i = 0; i < 3; ++i)
#pragma unroll
                for (int j = 0; j < 3; ++j) {
                    float2 e = colv[k + i * d][j];
                    SE = fmaf(WE[i * 3 + j], e.x, SE);
                    SD = fmaf(WD[i * 3 + j], e.y, SD);
                }
            float me = -(__logf(fmaxf(SE, SFLOOR)) + MSHIFT) * INV_BETA;
            float md =  (__logf(fmaxf(SD, SFLOOR)) + MSHIFT) * INV_BETA;
            s[br]     += me; q[br]     = fmaf(me, me, q[br]);
            s[br + 3] += md; q[br + 3] = fmaf(md, md, q[br + 3]);
        }
    }
    const int lane = tid & 63, wv = tid >> 6;
#pragma unroll
    for (int v = 0; v < 6; ++v) {
        float a = s[v], b2 = q[v];
#pragma unroll
        for (int off = 32; off; off >>= 1) {
            a  += __shfl_down(a, off, 64);
            b2 += __shfl_down(b2, off, 64);
        }
        if (lane == 0) { redS[wv][v] = a; redQ[wv][v] = b2; }
    }
    __syncthreads();
    if (tid < 6)
        atomicAdd(&sum[tid * 64 + c], redS[0][tid] + redS[1][tid] + redS[2][tid] + redS[3][tid]);
    else if (tid < 12) {
        int v = tid - 6;
        atomicAdd(&sqs[v * 64 + c], redQ[0][v] + redQ[1][v] + redQ[2][v] + redQ[3][v]);
    }
}

__global__ void k_alpha(const float* __restrict__ sum, const float* __restrict__ sqs,
                        const float* __restrict__ bn_ge,
                        const float* __restrict__ bn_gd,
                        const float* __restrict__ conve,
                        const float* __restrict__ convd,
                        float* __restrict__ alpha) {
    int tid = threadIdx.x;
    if (tid >= 384) return;
    float mean = sum[tid] * (1.0f / N1);
    float var  = sqs[tid] * (1.0f / N1) - mean * mean;
    float inv  = rsqrtf(fmaxf(var, 0.f) + EPSB);
    float g, cw, sgn;
    if (tid < 192) { g = bn_ge[tid];       cw = conve[tid];       sgn = -1.f; }
    else           { g = bn_gd[tid - 192]; cw = convd[tid - 192]; sgn =  1.f; }
    alpha[tid] = sgn * cw * g * inv * INV_BETA;
}

__global__ __launch_bounds__(256) void k_reduce_c(
    const float* __restrict__ x, const float* __restrict__ wg,
    const float* __restrict__ alpha, float* __restrict__ ye, float* __restrict__ yd) {
    __shared__ float2 E[TDIM * TSTR];
    const int tid = threadIdx.x;
    const int t = blockIdx.x;             // 36 tiles
    const int bz = blockIdx.y;            // b*8 + chunk
    const int b = bz >> 3, chunk = bz & 7;
    const int h0 = (t / NTW) * TILE, w0 = (t % NTW) * TILE;
    const int px = (tid & 31) + HALO;
    const int py0 = (tid >> 5) * 4;
    const float em0 = __expf(-MSHIFT);
    float accE[4] = {0,0,0,0}, accD[4] = {0,0,0,0};

    for (int ci = 0; ci < 8; ++ci) {
        const int c = chunk * 8 + ci;
        const float* xp = x + (size_t)(b * 64 + c) * HWn;
        __syncthreads();
        for (int l = tid; l < TDIM * TDIM; l += 256) {
            int r = l / TDIM, cc = l - r * TDIM;
            int gh = h0 - HALO + r, gw = w0 - HALO + cc;
            float2 e;
            if (gh >= 0 && gh < Hn && gw >= 0 && gw < Wn) {
                float bx = BETA * xp[gh * Wn + gw];
                e.x = __expf(-bx - MSHIFT);
                e.y = __expf(bx - MSHIFT);
            } else { e.x = em0; e.y = em0; }
            E[r * TSTR + cc] = e;
        }
        __syncthreads();
#pragma unroll
        for (int br = 0; br < 3; ++br) {
            const int d = br + 1;
            const float aE = alpha[br * 64 + c];
            const float aD = alpha[(br + 3) * 64 + c];
            float WE[9], WD[9];
#pragma unroll
            for (int k2 = 0; k2 < 9; ++k2) {
                WE[k2] = wg[(br * 64 + c) * 9 + k2];
                WD[k2] = wg[((br + 3) * 64 + c) * 9 + k2];
            }
            const int nr = 4 + 2 * d;
            float2 colv[10][3];
#pragma unroll
            for (int r = 0; r < nr; ++r)
#pragma unroll
                for (int j = 0; j < 3; ++j)
                    colv[r][j] = E[(py0 - d + r + HALO) * TSTR + px + (j - 1) * d];
#pragma unroll
            for (int k = 0; k < 4; ++k) {
                float SE = 0.f, SD = 0.f;
#pragma unroll
                for (int i = 0; i < 3; ++i)
#pragma unroll
                    for (int j = 0; j < 3; ++j) {
                        float2 e = colv[k + i * d][j];
                        SE = fmaf(WE[i * 3 + j], e.x, SE);
                        SD = fmaf(WD[i * 3 + j], e.y, SD);
                    }
                accE[k] = fmaf(aE, __logf(fmaxf(SE, SFLOOR)), accE[k]);
                accD[k] = fmaf(aD, __logf(fmaxf(SD, SFLOOR)), accD[k]);
            }
        }
    }
#pragma unroll
    for (int k = 0; k < 4; ++k) {
        int idx = b * HWn + (h0 + py0 + k) * Wn + (w0 + px - HALO);
        atomicAdd(&ye[idx], accE[k]);
        atomicAdd(&yd[idx], accD[k]);
    }
}

__global__ __launch_bounds__(256) void k_fstats(const float* __restrict__ ye,
                                                const float* __restrict__ yd,
                                                float* __restrict__ scal) {
    int i = blockIdx.x * 256 + threadIdx.x;
    float a = ye[i], b = yd[i];
    float v[4] = {a, a * a, b, b * b};
    __shared__ float red[4][4];
    int lane = threadIdx.x & 63, wv = threadIdx.x >> 6;
#pragma unroll
    for (int k = 0; k < 4; ++k) {
        float tv = v[k];
#pragma unroll
        for (int off = 32; off; off >>= 1) tv += __shfl_down(tv, off, 64);
        if (lane == 0) red[wv][k] = tv;
    }
    __syncthreads();
    if (threadIdx.x < 4)
        atomicAdd(&scal[threadIdx.x],
                  red[0][threadIdx.x] + red[1][threadIdx.x] + red[2][threadIdx.x] + red[3][threadIdx.x]);
}

__global__ __launch_bounds__(256) void k_final(
    const float* __restrict__ ye, const float* __restrict__ yd,
    const float* __restrict__ scal,
    const float* __restrict__ g_e, const float* __restrict__ b_e,
    const float* __restrict__ g_d, const float* __restrict__ b_d,
    float* __restrict__ out) {
    int i = blockIdx.x * 256 + threadIdx.x;  // < 294912
    float me_ = scal[0] * (1.0f / N1);
    float ve  = scal[1] * (1.0f / N1) - me_ * me_;
    float ie  = rsqrtf(fmaxf(ve, 0.f) + EPSB);
    float md_ = scal[2] * (1.0f / N1);
    float vd  = scal[3] * (1.0f / N1) - md_ * md_;
    float idv = rsqrtf(fmaxf(vd, 0.f) + EPSB);
    float ge = g_e[0], be = b_e[0];
    float gd = g_d[0], bd = b_d[0];
    int b = i / HWn, rem = i - b * HWn;
    float oe = fmaxf(ge * (ye[i] - me_) * ie + be, 0.f);
    float od = fmaxf(gd * (yd[i] - md_) * idv + bd, 0.f);
    out[(size_t)(b * 2) * HWn + rem]     = oe;
    out[(size_t)(b * 2 + 1) * HWn + rem] = od;
}

extern "C" void kernel_launch(void* const* d_in, const int* in_sizes, int n_in,
                              void* d_out, int out_size, void* d_ws, size_t ws_size,
                              hipStream_t stream) {
    const float* x     = (const float*)d_in[0];
    const float* we    = (const float*)d_in[1];
    const float* wd    = (const float*)d_in[2];
    const float* bn_ge = (const float*)d_in[3];
    const float* bn_gd = (const float*)d_in[5];
    const float* conve = (const float*)d_in[7];
    const float* convd = (const float*)d_in[8];
    const float* g_e   = (const float*)d_in[9];
    const float* b_e   = (const float*)d_in[10];
    const float* g_d   = (const float*)d_in[11];
    const float* b_d   = (const float*)d_in[12];
    float* ws = (float*)d_ws;

    hipMemsetAsync(d_ws, 0, (size_t)WS_TOTAL * sizeof(float), stream);
    hipLaunchKernelGGL(k_wexp, dim3(14), dim3(256), 0, stream, we, wd, ws + WS_WG);
    hipLaunchKernelGGL(k_morph_stats, dim3(36, 512), dim3(256), 0, stream,
                       x, ws + WS_WG, ws + WS_SUM, ws + WS_SQS);
    hipLaunchKernelGGL(k_alpha, dim3(1), dim3(384), 0, stream,
                       ws + WS_SUM, ws + WS_SQS, bn_ge, bn_gd, conve, convd, ws + WS_ALPHA);
    hipLaunchKernelGGL(k_reduce_c, dim3(36, 64), dim3(256), 0, stream,
                       x, ws + WS_WG, ws + WS_ALPHA, ws + WS_YE, ws + WS_YD);
    hipLaunchKernelGGL(k_fstats, dim3(1152), dim3(256), 0, stream,
                       ws + WS_YE, ws + WS_YD, ws + WS_SCAL);
    hipLaunchKernelGGL(k_final, dim3(1152), dim3(256), 0, stream,
                       ws + WS_YE, ws + WS_YD, ws + WS_SCAL, g_e, b_e, g_d, b_d,
                       (float*)d_out);
}